// Round 7
// baseline (380.445 us; speedup 1.0000x reference)
//
#include <hip/hip_runtime.h>
#include <stdint.h>

#define CCH 64
#define HWPIX 65536
#define NBINS 256

typedef float f4 __attribute__((ext_vector_type(4)));

#define GLDS16(gp, lp)                                                        \
    __builtin_amdgcn_global_load_lds(                                         \
        (const __attribute__((address_space(1))) uint32_t*)(gp),              \
        (__attribute__((address_space(3))) uint32_t*)(lp), 16, 0, 0)

// ws layout (float slots):
// [0    .. 1023] : dominant bins, int32, B*C entries
// [1024 .. 5119] : WcolT[o*64+c] = W1[o*64+c] * inv1[o]
// [5120 .. 5183] : base_pre[o]
// [5184 .. 5247] : w2[o]
// [5248 .. 5251] : scalars {inv2, beta2p, b2, s_empty}
// [5312 .. 5375] : s1[c]  = sigmoid for single-hit mask {c}
// [5400 .. 5415] : per-image hist-done counters (int)
// [8192 ..12287] : s2[c1*64+c2] = sigmoid for two-hit mask {c1,c2}

__global__ __launch_bounds__(64) void precomp_kernel(
    const float* __restrict__ w1, const float* __restrict__ b1,
    const float* __restrict__ g1, const float* __restrict__ be1,
    const float* __restrict__ m1, const float* __restrict__ v1,
    const float* __restrict__ w2, const float* __restrict__ b2,
    const float* __restrict__ g2, const float* __restrict__ be2,
    const float* __restrict__ m2, const float* __restrict__ v2,
    float* __restrict__ ws)
{
    int o = threadIdx.x;  // 0..63
    if (o < 16) ((int*)ws)[5400 + o] = 0;      // reset per-image counters
    float inv1 = g1[o] * rsqrtf(v1[o] + 1e-5f);
    float S = 0.f;
    for (int c = 0; c < CCH; ++c) S += w1[o * CCH + c];
    float beta1p = be1[o] - m1[o] * inv1;
    float base_pre = (S + b1[o]) * inv1 + beta1p;
    for (int c = 0; c < CCH; ++c) ws[1024 + o * CCH + c] = w1[o * CCH + c] * inv1;
    ws[5120 + o] = base_pre;
    float w2o = w2[o];
    ws[5184 + o] = w2o;
    float t = fmaxf(base_pre, 0.f) * w2o;
    #pragma unroll
    for (int off = 32; off > 0; off >>= 1) t += __shfl_down(t, off, 64);
    if (o == 0) {
        float inv2 = g2[0] * rsqrtf(v2[0] + 1e-5f);
        float beta2p = be2[0] - m2[0] * inv2;
        float z = (t + b2[0]) * inv2 + beta2p;
        ws[5248] = inv2;
        ws[5249] = beta2p;
        ws[5250] = b2[0];
        ws[5251] = 1.f / (1.f + expf(-z));
    }
    __syncthreads();
    // s1 table
    {
        int c = o;
        float t1 = 0.f;
        for (int oo = 0; oo < CCH; ++oo) {
            float acc = ws[5120 + oo] - ws[1024 + oo * CCH + c];
            t1 += fmaxf(acc, 0.f) * ws[5184 + oo];
        }
        float z = (t1 + ws[5250]) * ws[5248] + ws[5249];
        ws[5312 + c] = 1.f / (1.f + expf(-z));
    }
}

// s2 table: one block per c1, one thread per c2 (subtraction order matches
// the runtime fallback loop: base - w[c1] - w[c2], c1 < c2).
__global__ __launch_bounds__(64) void precomp2_kernel(float* __restrict__ ws)
{
    int c1 = blockIdx.x, c2 = threadIdx.x;
    float t = 0.f;
    for (int o = 0; o < CCH; ++o) {
        float acc = ws[5120 + o] - ws[1024 + o * CCH + c1] - ws[1024 + o * CCH + c2];
        t += fmaxf(acc, 0.f) * ws[5184 + o];
    }
    float z = (t + ws[5250]) * ws[5248] + ws[5249];
    ws[8192 + c1 * CCH + c2] = 1.f / (1.f + expf(-z));
}

// Fused hist+main, cooperative. Block (g = img, r = channel):
// Phase 1: full 256-bin histogram + argmax of (g,r)  -> dom[g*64+r], release-count.
// Wait:    spin until all 64 channels of image g published.
// Phase 2: 16 main chunks (64ch x 64px) of image g, R4-proven body.
__global__ __launch_bounds__(256, 8) void fused_kernel(
    const float* __restrict__ x, float* __restrict__ ws, float* __restrict__ out)
{
    __shared__ __align__(16) unsigned char smem[18496];
    int tid = threadIdx.x;
    int g = blockIdx.x >> 6;     // image
    int r = blockIdx.x & 63;     // channel for hist; chunk range for main
    int bc = g * CCH + r;

    int* domp = (int*)ws;
    int* cntp = (int*)ws + 5400;

    // ---- Phase 1: histogram + argmax (R4 hist body) ----
    {
        unsigned (*h)[NBINS + 1] = (unsigned(*)[NBINS + 1])smem;   // 16.4 KB
        unsigned long long* red = (unsigned long long*)(smem + 16448); // 2 KB
        const float4* xp = (const float4*)(x + (size_t)bc * HWPIX);

        for (int i = tid; i < 16 * (NBINS + 1); i += 256) ((unsigned*)h)[i] = 0;
        __syncthreads();

        unsigned* hmine = h[tid >> 4];
        const float scale = 256.0f / 255.0f;
        #pragma unroll 4
        for (int t = 0; t < HWPIX / 4 / 256; ++t) {
            float4 v = xp[t * 256 + tid];
            float vv[4] = {v.x, v.y, v.z, v.w};
            #pragma unroll
            for (int j = 0; j < 4; ++j) {
                float f = vv[j];
                if (f >= 0.f && f <= 255.f) {
                    int bi = (int)(f * scale);
                    bi = bi > NBINS - 1 ? NBINS - 1 : bi;
                    atomicAdd(&hmine[bi], 1u);
                }
            }
        }
        __syncthreads();

        unsigned cnt = 0;
        #pragma unroll
        for (int k = 0; k < 16; ++k) cnt += h[k][tid];
        red[tid] = ((unsigned long long)cnt << 32) | (unsigned)(NBINS - 1 - tid);
        __syncthreads();
        #pragma unroll
        for (int s = 128; s > 0; s >>= 1) {
            if (tid < s) {
                unsigned long long a = red[tid], b2 = red[tid + s];
                red[tid] = a > b2 ? a : b2;
            }
            __syncthreads();
        }
        if (tid == 0) {
            int dval = (NBINS - 1) - (int)(red[0] & 0xffffffffu);
            __hip_atomic_store(&domp[bc], dval, __ATOMIC_RELAXED,
                               __HIP_MEMORY_SCOPE_AGENT);
            __hip_atomic_fetch_add(&cntp[g], 1, __ATOMIC_RELEASE,
                                   __HIP_MEMORY_SCOPE_AGENT);
        }
    }

    // ---- wait for the whole image's dominant bins ----
    if (tid == 0) {
        while (__hip_atomic_load(&cntp[g], __ATOMIC_ACQUIRE,
                                 __HIP_MEMORY_SCOPE_AGENT) < CCH)
            __builtin_amdgcn_s_sleep(16);
    }
    __syncthreads();

    // ---- Phase 2: main chunks (R4 main body) ----
    float*    tile = (float*)smem;                 // 16 KB (reuses hist LDS)
    float*    ss   = (float*)(smem + 16384);       // 256 B
    float*    df   = (float*)(smem + 16640);       // 256 B
    unsigned* pm   = (unsigned*)(smem + 16896);    // 4*64 = 1 KB

    if (tid < CCH)
        df[tid] = (float)__hip_atomic_load(&domp[g * CCH + tid], __ATOMIC_RELAXED,
                                           __HIP_MEMORY_SCOPE_AGENT);
    __syncthreads();

    const f4* xb4 = (const f4*)(x + ((size_t)g << 22));
    f4*       ob4 = (f4*)(out + ((size_t)g << 22));

    for (int jj = 0; jj < 16; ++jj) {
        int j = (r << 4) + jj;                     // chunk index in image
        #pragma unroll
        for (int k = 0; k < 4; ++k) {
            int id = (k << 8) + tid;
            int c = id >> 4, col = id & 15;
            GLDS16(xb4 + ((size_t)c << 14) + (j << 4) + col, tile + (id << 2));
        }
        __syncthreads();                           // drains GLDS (vmcnt 0)

        {   // mask: each wave 16 channels x 64 px, conflict-free columns
            int part = tid >> 6, px = tid & 63;
            unsigned mloc = 0;
            #pragma unroll
            for (int cc = 0; cc < 16; ++cc) {
                int c = (part << 4) | cc;
                float v = tile[(c << 6) | px];
                float d = df[c];
                mloc |= (unsigned)(v >= d && v < d + 1.0f) << cc;
            }
            pm[(part << 6) | px] = mloc;
        }
        __syncthreads();

        if (tid < CCH) {   // wave 0: combine masks, sigmoid per pixel
            int px = tid;
            unsigned long long m = (unsigned long long)pm[px]
                | ((unsigned long long)pm[64 + px] << 16)
                | ((unsigned long long)pm[128 + px] << 32)
                | ((unsigned long long)pm[192 + px] << 48);
            float s;
            if (m == 0ull) {
                s = ws[5251];
            } else {
                int c1 = __builtin_ctzll(m);
                unsigned long long r1 = m & (m - 1);
                if (r1 == 0ull) {
                    s = ws[5312 + c1];
                } else {
                    int c2 = __builtin_ctzll(r1);
                    unsigned long long r2 = r1 & (r1 - 1);
                    if (r2 == 0ull) {
                        s = ws[8192 + (c1 << 6) + c2];
                    } else {
                        float t = 0.f;
                        for (int o = 0; o < CCH; ++o) {
                            float acc = ws[5120 + o];
                            unsigned long long mm = m;
                            const float* row = ws + 1024 + (o << 6);
                            while (mm) {
                                int c = __builtin_ctzll(mm);
                                mm &= mm - 1;
                                acc -= row[c];
                            }
                            t += fmaxf(acc, 0.f) * ws[5184 + o];
                        }
                        float z = (t + ws[5250]) * ws[5248] + ws[5249];
                        s = 1.f / (1.f + expf(-z));
                    }
                }
            }
            ss[px] = s;
        }
        __syncthreads();

        #pragma unroll
        for (int k = 0; k < 4; ++k) {
            int id = (k << 8) + tid;
            int c = id >> 4, col = id & 15;
            f4 v = *(const f4*)&tile[id << 2];
            f4 sv = *(const f4*)&ss[col << 2];
            v *= sv;
            __builtin_nontemporal_store(v, &ob4[((size_t)c << 14) + (j << 4) + col]);
        }
        __syncthreads();   // tile safe to overwrite next iteration
    }
}

extern "C" void kernel_launch(void* const* d_in, const int* in_sizes, int n_in,
                              void* d_out, int out_size, void* d_ws, size_t ws_size,
                              hipStream_t stream) {
    const float* x   = (const float*)d_in[0];
    const float* w1  = (const float*)d_in[1];
    const float* b1  = (const float*)d_in[2];
    const float* g1  = (const float*)d_in[3];
    const float* be1 = (const float*)d_in[4];
    const float* m1  = (const float*)d_in[5];
    const float* v1  = (const float*)d_in[6];
    const float* w2  = (const float*)d_in[7];
    const float* b2  = (const float*)d_in[8];
    const float* g2  = (const float*)d_in[9];
    const float* be2 = (const float*)d_in[10];
    const float* m2  = (const float*)d_in[11];
    const float* v2  = (const float*)d_in[12];

    float* ws  = (float*)d_ws;
    float* outp = (float*)d_out;

    int B = in_sizes[0] / (CCH * HWPIX);     // 16

    precomp_kernel<<<1, 64, 0, stream>>>(w1, b1, g1, be1, m1, v1,
                                         w2, b2, g2, be2, m2, v2, ws);
    precomp2_kernel<<<CCH, 64, 0, stream>>>(ws);

    void* args[] = { (void*)&x, (void*)&ws, (void*)&outp };
    hipLaunchCooperativeKernel((void*)fused_kernel, dim3(B * CCH), dim3(256),
                               args, 0, stream);
}

// Round 8
// 176.634 us; speedup vs baseline: 2.1539x; 2.1539x over previous
//
#include <hip/hip_runtime.h>
#include <stdint.h>

#define CCH 64
#define HWPIX 65536
#define NBINS 256

typedef float f4 __attribute__((ext_vector_type(4)));

#define GLDS16(gp, lp)                                                        \
    __builtin_amdgcn_global_load_lds(                                         \
        (const __attribute__((address_space(1))) uint32_t*)(gp),              \
        (__attribute__((address_space(3))) uint32_t*)(lp), 16, 0, 0)

// ws layout (float slots):
// [0    .. 1023] : dominant bins, int32, B*C entries
// [1024 .. 5119] : WcolT[o*64+c] = W1[o*64+c] * inv1[o]
// [5120 .. 5183] : base_pre[o]
// [5184 .. 5247] : w2[o]
// [5248 .. 5251] : scalars {inv2, beta2p, b2, s_empty}
// [5312 .. 5375] : s1[c]  = sigmoid for single-hit mask {c}
// [8192 ..12287] : s2[c1*64+c2] = sigmoid for two-hit mask {c1,c2}
// [16384 ..     ]: ghist, B*C*256 uint32 (1 MB) — split-hist accumulators

__global__ __launch_bounds__(64) void precomp_kernel(
    const float* __restrict__ w1, const float* __restrict__ b1,
    const float* __restrict__ g1, const float* __restrict__ be1,
    const float* __restrict__ m1, const float* __restrict__ v1,
    const float* __restrict__ w2, const float* __restrict__ b2,
    const float* __restrict__ g2, const float* __restrict__ be2,
    const float* __restrict__ m2, const float* __restrict__ v2,
    float* __restrict__ ws)
{
    int o = threadIdx.x;  // 0..63
    float inv1 = g1[o] * rsqrtf(v1[o] + 1e-5f);
    float S = 0.f;
    for (int c = 0; c < CCH; ++c) S += w1[o * CCH + c];
    float beta1p = be1[o] - m1[o] * inv1;
    float base_pre = (S + b1[o]) * inv1 + beta1p;
    for (int c = 0; c < CCH; ++c) ws[1024 + o * CCH + c] = w1[o * CCH + c] * inv1;
    ws[5120 + o] = base_pre;
    float w2o = w2[o];
    ws[5184 + o] = w2o;
    float t = fmaxf(base_pre, 0.f) * w2o;
    #pragma unroll
    for (int off = 32; off > 0; off >>= 1) t += __shfl_down(t, off, 64);
    if (o == 0) {
        float inv2 = g2[0] * rsqrtf(v2[0] + 1e-5f);
        float beta2p = be2[0] - m2[0] * inv2;
        float z = (t + b2[0]) * inv2 + beta2p;
        ws[5248] = inv2;
        ws[5249] = beta2p;
        ws[5250] = b2[0];
        ws[5251] = 1.f / (1.f + expf(-z));
    }
    __syncthreads();
    // s1 table
    {
        int c = o;
        float t1 = 0.f;
        for (int oo = 0; oo < CCH; ++oo) {
            float acc = ws[5120 + oo] - ws[1024 + oo * CCH + c];
            t1 += fmaxf(acc, 0.f) * ws[5184 + oo];
        }
        float z = (t1 + ws[5250]) * ws[5248] + ws[5249];
        ws[5312 + c] = 1.f / (1.f + expf(-z));
    }
}

// s2 table + (optionally) zero the split-hist accumulators.
__global__ __launch_bounds__(64) void precomp2_kernel(float* __restrict__ ws,
                                                      int do_zero)
{
    int c1 = blockIdx.x, c2 = threadIdx.x;
    if (do_zero) {
        unsigned* gh = (unsigned*)((char*)ws + 65536);
        int lin = c1 * 64 + c2;               // 4096 threads x 64 ints = 1 MB
        #pragma unroll
        for (int k = 0; k < 64; ++k) gh[lin * 64 + k] = 0u;
    }
    float t = 0.f;
    for (int o = 0; o < CCH; ++o) {
        float acc = ws[5120 + o] - ws[1024 + o * CCH + c1] - ws[1024 + o * CCH + c2];
        t += fmaxf(acc, 0.f) * ws[5184 + o];
    }
    float z = (t + ws[5250]) * ws[5248] + ws[5249];
    ws[8192 + c1 * CCH + c2] = 1.f / (1.f + expf(-z));
}

// Split hist: 2 blocks per (b,c) plane (half plane each, 8 blocks/CU for
// 2x the latency-hiding TLP), device-atomic merge into ghist.
__global__ __launch_bounds__(256) void hist2_kernel(
    const float* __restrict__ x, unsigned* __restrict__ ghist)
{
    __shared__ unsigned h[16][NBINS + 1];
    int tid = threadIdx.x;
    int bc = blockIdx.x >> 1, half = blockIdx.x & 1;
    const float4* xp = (const float4*)(x + (size_t)bc * HWPIX + (half << 15));

    for (int i = tid; i < 16 * (NBINS + 1); i += 256) ((unsigned*)h)[i] = 0;
    __syncthreads();

    unsigned* hmine = h[tid >> 4];
    const float scale = 256.0f / 255.0f;
    #pragma unroll 4
    for (int t = 0; t < HWPIX / 8 / 256; ++t) {       // 32 iterations
        float4 v = xp[t * 256 + tid];
        float vv[4] = {v.x, v.y, v.z, v.w};
        #pragma unroll
        for (int j = 0; j < 4; ++j) {
            float f = vv[j];
            if (f >= 0.f && f <= 255.f) {
                int bi = (int)(f * scale);
                bi = bi > NBINS - 1 ? NBINS - 1 : bi;
                atomicAdd(&hmine[bi], 1u);
            }
        }
    }
    __syncthreads();

    unsigned cnt = 0;
    #pragma unroll
    for (int k = 0; k < 16; ++k) cnt += h[k][tid];
    if (cnt) atomicAdd(&ghist[bc * NBINS + tid], cnt);
}

// argmax over ghist -> dom (identical packed-key first-max tie rule).
__global__ __launch_bounds__(256) void argmax_kernel(
    const unsigned* __restrict__ ghist, int* __restrict__ dom)
{
    __shared__ unsigned long long red[NBINS];
    int tid = threadIdx.x, bc = blockIdx.x;
    unsigned cnt = ghist[bc * NBINS + tid];
    red[tid] = ((unsigned long long)cnt << 32) | (unsigned)(NBINS - 1 - tid);
    __syncthreads();
    #pragma unroll
    for (int s = 128; s > 0; s >>= 1) {
        if (tid < s) {
            unsigned long long a = red[tid], b = red[tid + s];
            red[tid] = a > b ? a : b;
        }
        __syncthreads();
    }
    if (tid == 0) dom[bc] = (NBINS - 1) - (int)(red[0] & 0xffffffffu);
}

// Fallback single-block-per-plane hist (R4 config) when ws is too small.
__global__ __launch_bounds__(256) void hist_kernel(
    const float* __restrict__ x, int* __restrict__ dom)
{
    __shared__ unsigned h[16][NBINS + 1];
    __shared__ unsigned long long red[NBINS];
    int tid = threadIdx.x;
    const float4* xp = (const float4*)(x + (size_t)blockIdx.x * HWPIX);

    for (int i = tid; i < 16 * (NBINS + 1); i += 256) ((unsigned*)h)[i] = 0;
    __syncthreads();

    unsigned* hmine = h[tid >> 4];
    const float scale = 256.0f / 255.0f;
    #pragma unroll 4
    for (int t = 0; t < HWPIX / 4 / 256; ++t) {
        float4 v = xp[t * 256 + tid];
        float vv[4] = {v.x, v.y, v.z, v.w};
        #pragma unroll
        for (int j = 0; j < 4; ++j) {
            float f = vv[j];
            if (f >= 0.f && f <= 255.f) {
                int bi = (int)(f * scale);
                bi = bi > NBINS - 1 ? NBINS - 1 : bi;
                atomicAdd(&hmine[bi], 1u);
            }
        }
    }
    __syncthreads();

    unsigned cnt = 0;
    #pragma unroll
    for (int k = 0; k < 16; ++k) cnt += h[k][tid];
    red[tid] = ((unsigned long long)cnt << 32) | (unsigned)(NBINS - 1 - tid);
    __syncthreads();
    #pragma unroll
    for (int s = 128; s > 0; s >>= 1) {
        if (tid < s) {
            unsigned long long a = red[tid], b = red[tid + s];
            red[tid] = a > b ? a : b;
        }
        __syncthreads();
    }
    if (tid == 0) dom[blockIdx.x] = (NBINS - 1) - (int)(red[0] & 0xffffffffu);
}

// Main: 64ch x 64px chunk per block, GLDS staging, merged mask+sigmoid
// (one barrier fewer), REVERSED chunk order for LLC hits, NT stores.
__global__ __launch_bounds__(256, 8) void main_kernel(
    const float* __restrict__ x, const float* __restrict__ ws,
    const int* __restrict__ dom, float* __restrict__ out)
{
    __shared__ __align__(16) float tile[CCH * 64];   // 16 KiB
    __shared__ float ss[64];
    __shared__ float df[CCH];

    int tid = threadIdx.x;
    int rc = (gridDim.x - 1) - blockIdx.x;   // reversed global chunk index
    int img = rc >> 10;
    int jc  = rc & 1023;                     // chunk within image

    const f4* xb4 = (const f4*)(x + ((size_t)img << 22));
    f4*       ob4 = (f4*)(out + ((size_t)img << 22));

    #pragma unroll
    for (int k = 0; k < 4; ++k) {
        int id = (k << 8) + tid;
        int c = id >> 4, col = id & 15;
        GLDS16(xb4 + ((size_t)c << 14) + (jc << 4) + col, tile + (id << 2));
    }
    if (tid < CCH) df[tid] = (float)dom[img * CCH + tid];
    __syncthreads();                         // drains GLDS; df visible

    // merged mask + sigmoid: 16 pixel-owner lanes per wave
    if ((tid & 63) < 16) {
        int px = ((tid >> 6) << 4) | (tid & 15);
        unsigned long long m = 0ull;
        #pragma unroll
        for (int c = 0; c < CCH; ++c) {
            float v = tile[(c << 6) | px];
            float d = df[c];
            m |= (unsigned long long)(v >= d && v < d + 1.0f) << c;
        }
        float s;
        if (m == 0ull) {
            s = ws[5251];
        } else {
            int c1 = __builtin_ctzll(m);
            unsigned long long r1 = m & (m - 1);
            if (r1 == 0ull) {
                s = ws[5312 + c1];
            } else {
                int c2 = __builtin_ctzll(r1);
                unsigned long long r2 = r1 & (r1 - 1);
                if (r2 == 0ull) {
                    s = ws[8192 + (c1 << 6) + c2];
                } else {
                    float t = 0.f;
                    for (int o = 0; o < CCH; ++o) {
                        float acc = ws[5120 + o];
                        unsigned long long mm = m;
                        const float* row = ws + 1024 + (o << 6);
                        while (mm) {
                            int c = __builtin_ctzll(mm);
                            mm &= mm - 1;
                            acc -= row[c];
                        }
                        t += fmaxf(acc, 0.f) * ws[5184 + o];
                    }
                    float z = (t + ws[5250]) * ws[5248] + ws[5249];
                    s = 1.f / (1.f + expf(-z));
                }
            }
        }
        ss[px] = s;
    }
    __syncthreads();

    #pragma unroll
    for (int k = 0; k < 4; ++k) {
        int id = (k << 8) + tid;
        int c = id >> 4, col = id & 15;
        f4 v = *(const f4*)&tile[id << 2];
        f4 sv = *(const f4*)&ss[col << 2];
        v *= sv;
        __builtin_nontemporal_store(v, &ob4[((size_t)c << 14) + (jc << 4) + col]);
    }
}

extern "C" void kernel_launch(void* const* d_in, const int* in_sizes, int n_in,
                              void* d_out, int out_size, void* d_ws, size_t ws_size,
                              hipStream_t stream) {
    const float* x   = (const float*)d_in[0];
    const float* w1  = (const float*)d_in[1];
    const float* b1  = (const float*)d_in[2];
    const float* g1  = (const float*)d_in[3];
    const float* be1 = (const float*)d_in[4];
    const float* m1  = (const float*)d_in[5];
    const float* v1  = (const float*)d_in[6];
    const float* w2  = (const float*)d_in[7];
    const float* b2  = (const float*)d_in[8];
    const float* g2  = (const float*)d_in[9];
    const float* be2 = (const float*)d_in[10];
    const float* m2  = (const float*)d_in[11];
    const float* v2  = (const float*)d_in[12];

    float* ws  = (float*)d_ws;
    int*   dom = (int*)d_ws;                        // aliases ws[0..1023]
    unsigned* ghist = (unsigned*)((char*)d_ws + 65536);
    float* outp = (float*)d_out;

    int B = in_sizes[0] / (CCH * HWPIX);            // 16
    bool split = ws_size >= (size_t)(65536 + B * CCH * NBINS * 4);

    precomp_kernel<<<1, 64, 0, stream>>>(w1, b1, g1, be1, m1, v1,
                                         w2, b2, g2, be2, m2, v2, ws);
    precomp2_kernel<<<CCH, 64, 0, stream>>>(ws, split ? 1 : 0);

    if (split) {
        hist2_kernel<<<B * CCH * 2, 256, 0, stream>>>(x, ghist);
        argmax_kernel<<<B * CCH, 256, 0, stream>>>(ghist, dom);
    } else {
        hist_kernel<<<B * CCH, 256, 0, stream>>>(x, dom);
    }
    main_kernel<<<B * 1024, 256, 0, stream>>>(x, ws, dom, outp);
}

// Round 9
// 170.735 us; speedup vs baseline: 2.2283x; 1.0346x over previous
//
#include <hip/hip_runtime.h>
#include <stdint.h>

#define CCH 64
#define HWPIX 65536
#define NBINS 256

typedef float f4 __attribute__((ext_vector_type(4)));
typedef unsigned u32x4 __attribute__((ext_vector_type(4)));

// ws layout (float slots):
// [0    .. 1023] : dominant bins, int32, B*C entries
// [1024 .. 5119] : WcolT[o*64+c] = W1[o*64+c] * inv1[o]
// [5120 .. 5183] : base_pre[o]
// [5184 .. 5247] : w2[o]
// [5248 .. 5251] : scalars {inv2, beta2p, b2, s_empty}
// [5312 .. 5375] : s1[c]  = sigmoid for single-hit mask {c}
// [8192 ..12287] : s2[c1*64+c2] = sigmoid for two-hit mask {c1,c2}

__global__ __launch_bounds__(64) void precomp_kernel(
    const float* __restrict__ w1, const float* __restrict__ b1,
    const float* __restrict__ g1, const float* __restrict__ be1,
    const float* __restrict__ m1, const float* __restrict__ v1,
    const float* __restrict__ w2, const float* __restrict__ b2,
    const float* __restrict__ g2, const float* __restrict__ be2,
    const float* __restrict__ m2, const float* __restrict__ v2,
    float* __restrict__ ws)
{
    int o = threadIdx.x;  // 0..63
    float inv1 = g1[o] * rsqrtf(v1[o] + 1e-5f);
    float S = 0.f;
    for (int c = 0; c < CCH; ++c) S += w1[o * CCH + c];
    float beta1p = be1[o] - m1[o] * inv1;
    float base_pre = (S + b1[o]) * inv1 + beta1p;
    for (int c = 0; c < CCH; ++c) ws[1024 + o * CCH + c] = w1[o * CCH + c] * inv1;
    ws[5120 + o] = base_pre;
    float w2o = w2[o];
    ws[5184 + o] = w2o;
    float t = fmaxf(base_pre, 0.f) * w2o;
    #pragma unroll
    for (int off = 32; off > 0; off >>= 1) t += __shfl_down(t, off, 64);
    if (o == 0) {
        float inv2 = g2[0] * rsqrtf(v2[0] + 1e-5f);
        float beta2p = be2[0] - m2[0] * inv2;
        float z = (t + b2[0]) * inv2 + beta2p;
        ws[5248] = inv2;
        ws[5249] = beta2p;
        ws[5250] = b2[0];
        ws[5251] = 1.f / (1.f + expf(-z));
    }
    __syncthreads();
    // s1 table
    {
        int c = o;
        float t1 = 0.f;
        for (int oo = 0; oo < CCH; ++oo) {
            float acc = ws[5120 + oo] - ws[1024 + oo * CCH + c];
            t1 += fmaxf(acc, 0.f) * ws[5184 + oo];
        }
        float z = (t1 + ws[5250]) * ws[5248] + ws[5249];
        ws[5312 + c] = 1.f / (1.f + expf(-z));
    }
}

// s2 table: one block per c1, one thread per c2 (subtraction order matches
// the runtime fallback loop: base - w[c1] - w[c2]).
__global__ __launch_bounds__(64) void precomp2_kernel(float* __restrict__ ws)
{
    int c1 = blockIdx.x, c2 = threadIdx.x;
    float t = 0.f;
    for (int o = 0; o < CCH; ++o) {
        float acc = ws[5120 + o] - ws[1024 + o * CCH + c1] - ws[1024 + o * CCH + c2];
        t += fmaxf(acc, 0.f) * ws[5184 + o];
    }
    float z = (t + ws[5250]) * ws[5248] + ws[5249];
    ws[8192 + c1 * CCH + c2] = 1.f / (1.f + expf(-z));
}

// One block per (b,c) image: 256-bin histogram + first-max argmax (R4 config).
__global__ __launch_bounds__(256) void hist_kernel(
    const float* __restrict__ x, int* __restrict__ dom)
{
    __shared__ unsigned h[16][NBINS + 1];
    __shared__ unsigned long long red[NBINS];
    int tid = threadIdx.x;
    const float4* xp = (const float4*)(x + (size_t)blockIdx.x * HWPIX);

    for (int i = tid; i < 16 * (NBINS + 1); i += 256) ((unsigned*)h)[i] = 0;
    __syncthreads();

    unsigned* hmine = h[tid >> 4];
    const float scale = 256.0f / 255.0f;
    #pragma unroll 4
    for (int t = 0; t < HWPIX / 4 / 256; ++t) {
        float4 v = xp[t * 256 + tid];
        float vv[4] = {v.x, v.y, v.z, v.w};
        #pragma unroll
        for (int j = 0; j < 4; ++j) {
            float f = vv[j];
            if (f >= 0.f && f <= 255.f) {
                int bi = (int)(f * scale);
                bi = bi > NBINS - 1 ? NBINS - 1 : bi;
                atomicAdd(&hmine[bi], 1u);
            }
        }
    }
    __syncthreads();

    unsigned cnt = 0;
    #pragma unroll
    for (int k = 0; k < 16; ++k) cnt += h[k][tid];
    red[tid] = ((unsigned long long)cnt << 32) | (unsigned)(NBINS - 1 - tid);
    __syncthreads();
    #pragma unroll
    for (int s = 128; s > 0; s >>= 1) {
        if (tid < s) {
            unsigned long long a = red[tid], b = red[tid + s];
            red[tid] = a > b ? a : b;
        }
        __syncthreads();
    }
    if (tid == 0) dom[blockIdx.x] = (NBINS - 1) - (int)(red[0] & 0xffffffffu);
}

// Register-resident main: x lives in 16 VGPRs per thread; LDS only carries
// the 8.5 KB mask exchange. 2 barriers/chunk, 8 blocks/CU, NT stores.
// Thread (g = tid>>4, col = tid&15) owns channels {g,g+16,g+32,g+48} x
// pixels {4col..4col+3} of the 64ch x 64px chunk.
__global__ __launch_bounds__(256, 8) void main_kernel(
    const float* __restrict__ x, const float* __restrict__ ws,
    const int* __restrict__ dom, float* __restrict__ out)
{
    __shared__ unsigned pmlo[16][64];
    __shared__ unsigned pmhi[16][64];
    __shared__ float ss[64];

    int tid = threadIdx.x;
    int rc = (gridDim.x - 1) - blockIdx.x;   // reversed order: LLC-hot first
    int img = rc >> 10;
    int jc  = rc & 1023;                     // chunk within image
    int g   = tid >> 4;                      // channel group
    int col = tid & 15;                      // float4 column
    int px0 = col << 2;

    const f4* xb4 = (const f4*)(x + ((size_t)img << 22));
    f4*       ob4 = (f4*)(out + ((size_t)img << 22));
    size_t base = ((size_t)jc << 4) + col;

    // 4 independent coalesced b128 loads -> registers
    f4 v0 = xb4[((size_t)(g     ) << 14) + base];
    f4 v1 = xb4[((size_t)(g + 16) << 14) + base];
    f4 v2 = xb4[((size_t)(g + 32) << 14) + base];
    f4 v3 = xb4[((size_t)(g + 48) << 14) + base];

    const int* domi = dom + img * CCH;
    float d0 = (float)domi[g];
    float d1 = (float)domi[g + 16];
    float d2 = (float)domi[g + 32];
    float d3 = (float)domi[g + 48];

    unsigned lo[4], hi[4];
    #pragma unroll
    for (int j = 0; j < 4; ++j) {
        unsigned l = 0, h = 0;
        l |= (unsigned)(v0[j] >= d0 && v0[j] < d0 + 1.0f) << g;
        l |= (unsigned)(v1[j] >= d1 && v1[j] < d1 + 1.0f) << (g + 16);
        h |= (unsigned)(v2[j] >= d2 && v2[j] < d2 + 1.0f) << g;
        h |= (unsigned)(v3[j] >= d3 && v3[j] < d3 + 1.0f) << (g + 16);
        lo[j] = l; hi[j] = h;
    }
    *(u32x4*)&pmlo[g][px0] = *(u32x4*)lo;
    *(u32x4*)&pmhi[g][px0] = *(u32x4*)hi;
    __syncthreads();

    if (tid < 64) {        // one lane per pixel: OR partials, sigmoid
        int px = tid;
        unsigned mlo = 0, mhi = 0;
        #pragma unroll
        for (int gg = 0; gg < 16; ++gg) {
            mlo |= pmlo[gg][px];
            mhi |= pmhi[gg][px];
        }
        unsigned long long m = ((unsigned long long)mhi << 32) | mlo;
        float s;
        if (m == 0ull) {
            s = ws[5251];
        } else {
            int c1 = __builtin_ctzll(m);
            unsigned long long r1 = m & (m - 1);
            if (r1 == 0ull) {
                s = ws[5312 + c1];
            } else {
                int c2 = __builtin_ctzll(r1);
                unsigned long long r2 = r1 & (r1 - 1);
                if (r2 == 0ull) {
                    s = ws[8192 + (c1 << 6) + c2];
                } else {
                    float t = 0.f;
                    for (int o = 0; o < CCH; ++o) {
                        float acc = ws[5120 + o];
                        unsigned long long mm = m;
                        const float* row = ws + 1024 + (o << 6);
                        while (mm) {
                            int c = __builtin_ctzll(mm);
                            mm &= mm - 1;
                            acc -= row[c];
                        }
                        t += fmaxf(acc, 0.f) * ws[5184 + o];
                    }
                    float z = (t + ws[5250]) * ws[5248] + ws[5249];
                    s = 1.f / (1.f + expf(-z));
                }
            }
        }
        ss[px] = s;
    }
    __syncthreads();

    f4 sv = *(const f4*)&ss[px0];
    v0 *= sv; v1 *= sv; v2 *= sv; v3 *= sv;
    __builtin_nontemporal_store(v0, &ob4[((size_t)(g     ) << 14) + base]);
    __builtin_nontemporal_store(v1, &ob4[((size_t)(g + 16) << 14) + base]);
    __builtin_nontemporal_store(v2, &ob4[((size_t)(g + 32) << 14) + base]);
    __builtin_nontemporal_store(v3, &ob4[((size_t)(g + 48) << 14) + base]);
}

extern "C" void kernel_launch(void* const* d_in, const int* in_sizes, int n_in,
                              void* d_out, int out_size, void* d_ws, size_t ws_size,
                              hipStream_t stream) {
    const float* x   = (const float*)d_in[0];
    const float* w1  = (const float*)d_in[1];
    const float* b1  = (const float*)d_in[2];
    const float* g1  = (const float*)d_in[3];
    const float* be1 = (const float*)d_in[4];
    const float* m1  = (const float*)d_in[5];
    const float* v1  = (const float*)d_in[6];
    const float* w2  = (const float*)d_in[7];
    const float* b2  = (const float*)d_in[8];
    const float* g2  = (const float*)d_in[9];
    const float* be2 = (const float*)d_in[10];
    const float* m2  = (const float*)d_in[11];
    const float* v2  = (const float*)d_in[12];

    float* ws  = (float*)d_ws;
    int*   dom = (int*)d_ws;                 // aliases ws[0..1023]
    float* outp = (float*)d_out;

    int B = in_sizes[0] / (CCH * HWPIX);     // 16

    precomp_kernel<<<1, 64, 0, stream>>>(w1, b1, g1, be1, m1, v1,
                                         w2, b2, g2, be2, m2, v2, ws);
    precomp2_kernel<<<CCH, 64, 0, stream>>>(ws);
    hist_kernel<<<B * CCH, 256, 0, stream>>>(x, dom);
    main_kernel<<<B * 1024, 256, 0, stream>>>(x, ws, dom, outp);
}